// Round 2
// baseline (1451.759 us; speedup 1.0000x reference)
//
#include <hip/hip_runtime.h>

#define N_NODES 100000
#define IN_DIM 256
#define OUT_DIM 64
#define INV_KEEP 1.1111111111111112f  // 1/0.9

// spmm1: h[row,:] += (keep ? x_val/0.9 : 0) * W[col,:]
// one 64-lane wave per nnz; lane = output dim. W staged in LDS (64 KB).
__global__ __launch_bounds__(256) void spmm1_kernel(
    const float* __restrict__ x_vals, const int* __restrict__ x_rows,
    const int* __restrict__ x_cols, const int* __restrict__ keep,
    const float* __restrict__ W, float* __restrict__ h, int nnz)
{
    __shared__ float Wl[IN_DIM * OUT_DIM];
    for (int i = threadIdx.x; i < IN_DIM * OUT_DIM; i += blockDim.x)
        Wl[i] = W[i];
    __syncthreads();

    const int lane   = threadIdx.x & 63;
    const int group  = (int)((blockIdx.x * blockDim.x + threadIdx.x) >> 6);
    const int stride = (int)((gridDim.x * blockDim.x) >> 6);

    for (int e = group; e < nnz; e += stride) {
        // wave-uniform scalars (all 64 lanes read same address -> broadcast)
        float v = (keep[e] != 0) ? x_vals[e] * INV_KEEP : 0.0f;
        if (v != 0.0f) {                       // wave-uniform branch
            int row = x_rows[e];
            int col = x_cols[e];
            atomicAdd(&h[(size_t)row * OUT_DIM + lane],
                      v * Wl[col * OUT_DIM + lane]);
        }
    }
}

// spmm2: out[row,:] += adj_val * h[col,:]
__global__ __launch_bounds__(256) void spmm2_kernel(
    const float* __restrict__ adj_vals, const int* __restrict__ adj_rows,
    const int* __restrict__ adj_cols, const float* __restrict__ h,
    float* __restrict__ out, int nnz)
{
    const int lane   = threadIdx.x & 63;
    const int group  = (int)((blockIdx.x * blockDim.x + threadIdx.x) >> 6);
    const int stride = (int)((gridDim.x * blockDim.x) >> 6);

    for (int e = group; e < nnz; e += stride) {
        float v = adj_vals[e];
        int row = adj_rows[e];
        int col = adj_cols[e];
        atomicAdd(&out[(size_t)row * OUT_DIM + lane],
                  v * h[(size_t)col * OUT_DIM + lane]);
    }
}

__global__ __launch_bounds__(256) void relu_kernel(float* __restrict__ out, int n)
{
    int i = (int)(blockIdx.x * blockDim.x + threadIdx.x);
    if (i < n) {
        float v = out[i];
        out[i] = v > 0.0f ? v : 0.0f;
    }
}

extern "C" void kernel_launch(void* const* d_in, const int* in_sizes, int n_in,
                              void* d_out, int out_size, void* d_ws, size_t ws_size,
                              hipStream_t stream)
{
    const float* x_vals   = (const float*)d_in[0];
    const int*   x_rows   = (const int*)d_in[1];
    const int*   x_cols   = (const int*)d_in[2];
    const float* adj_vals = (const float*)d_in[3];
    const int*   adj_rows = (const int*)d_in[4];
    const int*   adj_cols = (const int*)d_in[5];
    const float* W        = (const float*)d_in[6];
    const int*   keep     = (const int*)d_in[7];

    const int x_nnz = in_sizes[0];
    const int a_nnz = in_sizes[3];

    float* h   = (float*)d_ws;                      // [N, OUT_DIM] intermediate
    float* out = (float*)d_out;                     // [N, OUT_DIM] final

    const size_t h_bytes = (size_t)N_NODES * OUT_DIM * sizeof(float);

    hipMemsetAsync(h, 0, h_bytes, stream);
    hipMemsetAsync(out, 0, (size_t)out_size * sizeof(float), stream);

    spmm1_kernel<<<2048, 256, 0, stream>>>(x_vals, x_rows, x_cols, keep, W, h, x_nnz);
    spmm2_kernel<<<4096, 256, 0, stream>>>(adj_vals, adj_rows, adj_cols, h, out, a_nnz);
    relu_kernel<<<(out_size + 255) / 256, 256, 0, stream>>>(out, out_size);
}

// Round 3
// 1121.342 us; speedup vs baseline: 1.2947x; 1.2947x over previous
//
#include <hip/hip_runtime.h>

#define N_NODES 100000
#define IN_DIM 256
#define OUT_DIM 64
#define INV_KEEP 1.1111111111111112f  // 1/0.9

// ============================ CSR-build path ============================

// histogram of destination rows (optionally masked by keep)
__global__ __launch_bounds__(256) void hist_kernel(
    const int* __restrict__ rows, const int* __restrict__ keep,
    int* __restrict__ counts, int nnz)
{
    int i = blockIdx.x * blockDim.x + threadIdx.x;
    int stride = gridDim.x * blockDim.x;
    if (keep) {
        for (int e = i; e < nnz; e += stride)
            if (keep[e] != 0) atomicAdd(&counts[rows[e]], 1);
    } else {
        for (int e = i; e < nnz; e += stride)
            atomicAdd(&counts[rows[e]], 1);
    }
}

// single-block exclusive scan of counts[n] -> start[n+1]; also rewrites
// counts[i] = start[i] so the same array serves as the scatter cursor.
// block 0 handles (cx,sx), block 1 handles (ca,sa).
__global__ __launch_bounds__(1024) void scan2_kernel(
    int* __restrict__ cx, int* __restrict__ sx,
    int* __restrict__ ca, int* __restrict__ sa, int n)
{
    int* counts = (blockIdx.x == 0) ? cx : ca;
    int* start  = (blockIdx.x == 0) ? sx : sa;

    __shared__ int sums[1024];
    const int t = threadIdx.x;
    const int chunk = (n + 1023) / 1024;
    const int lo = t * chunk;
    const int hi = min(lo + chunk, n);

    int s = 0;
    for (int i = lo; i < hi; ++i) s += counts[i];
    sums[t] = s;
    __syncthreads();

    // Hillis-Steele inclusive scan
    for (int off = 1; off < 1024; off <<= 1) {
        int v = (t >= off) ? sums[t - off] : 0;
        __syncthreads();
        sums[t] += v;
        __syncthreads();
    }

    int run = (t > 0) ? sums[t - 1] : 0;
    for (int i = lo; i < hi; ++i) {
        int c = counts[i];
        start[i]  = run;
        counts[i] = run;   // cursor for scatter
        run += c;
    }
    if (t == 1023) start[n] = run;
}

// scatter x entries (dropout applied; dropped entries skipped entirely)
__global__ __launch_bounds__(256) void scatter_x_kernel(
    const float* __restrict__ xv, const int* __restrict__ xr,
    const int* __restrict__ xc, const int* __restrict__ keep,
    int* __restrict__ cursor, float2* __restrict__ out, int nnz)
{
    int i = blockIdx.x * blockDim.x + threadIdx.x;
    int stride = gridDim.x * blockDim.x;
    for (int e = i; e < nnz; e += stride) {
        if (keep[e] == 0) continue;
        int pos = atomicAdd(&cursor[xr[e]], 1);
        out[pos] = make_float2(xv[e] * INV_KEEP, __int_as_float(xc[e]));
    }
}

__global__ __launch_bounds__(256) void scatter_a_kernel(
    const float* __restrict__ av, const int* __restrict__ ar,
    const int* __restrict__ ac,
    int* __restrict__ cursor, float2* __restrict__ out, int nnz)
{
    int i = blockIdx.x * blockDim.x + threadIdx.x;
    int stride = gridDim.x * blockDim.x;
    for (int e = i; e < nnz; e += stride) {
        int pos = atomicAdd(&cursor[ar[e]], 1);
        out[pos] = make_float2(av[e], __int_as_float(ac[e]));
    }
}

// one 64-lane wave per output row; lane = output dim; no atomics.
__global__ __launch_bounds__(256) void spmm1_csr_kernel(
    const int* __restrict__ xs_start, const float2* __restrict__ xs,
    const float* __restrict__ W, float* __restrict__ h)
{
    const int wave = (int)((blockIdx.x * blockDim.x + threadIdx.x) >> 6);
    const int lane = threadIdx.x & 63;
    if (wave >= N_NODES) return;

    const int s = xs_start[wave];
    const int e = xs_start[wave + 1];
    float acc = 0.0f;
    for (int j = s; j < e; ++j) {
        float2 p = xs[j];                       // wave-uniform 8B load
        int c = __float_as_int(p.y);
        acc += p.x * W[c * OUT_DIM + lane];     // 256B coalesced, L2-hit
    }
    h[(size_t)wave * OUT_DIM + lane] = acc;
}

__global__ __launch_bounds__(256) void spmm2_csr_kernel(
    const int* __restrict__ as_start, const float2* __restrict__ as,
    const float* __restrict__ h, float* __restrict__ out)
{
    const int wave = (int)((blockIdx.x * blockDim.x + threadIdx.x) >> 6);
    const int lane = threadIdx.x & 63;
    if (wave >= N_NODES) return;

    const int s = as_start[wave];
    const int e = as_start[wave + 1];
    float acc = 0.0f;
    for (int j = s; j < e; ++j) {
        float2 p = as[j];                       // wave-uniform 8B load
        int c = __float_as_int(p.y);
        acc += p.x * h[(size_t)c * OUT_DIM + lane];  // 256B gather, L3-resident
    }
    out[(size_t)wave * OUT_DIM + lane] = acc > 0.0f ? acc : 0.0f;  // fused relu
}

// ============================ fallback (atomic) path ============================

__global__ __launch_bounds__(256) void spmm1_atomic_kernel(
    const float* __restrict__ x_vals, const int* __restrict__ x_rows,
    const int* __restrict__ x_cols, const int* __restrict__ keep,
    const float* __restrict__ W, float* __restrict__ h, int nnz)
{
    const int lane   = threadIdx.x & 63;
    const int group  = (int)((blockIdx.x * blockDim.x + threadIdx.x) >> 6);
    const int stride = (int)((gridDim.x * blockDim.x) >> 6);
    for (int e = group; e < nnz; e += stride) {
        float v = (keep[e] != 0) ? x_vals[e] * INV_KEEP : 0.0f;
        if (v != 0.0f) {
            int row = x_rows[e];
            int col = x_cols[e];
            atomicAdd(&h[(size_t)row * OUT_DIM + lane], v * W[col * OUT_DIM + lane]);
        }
    }
}

__global__ __launch_bounds__(256) void spmm2_atomic_kernel(
    const float* __restrict__ adj_vals, const int* __restrict__ adj_rows,
    const int* __restrict__ adj_cols, const float* __restrict__ h,
    float* __restrict__ out, int nnz)
{
    const int lane   = threadIdx.x & 63;
    const int group  = (int)((blockIdx.x * blockDim.x + threadIdx.x) >> 6);
    const int stride = (int)((gridDim.x * blockDim.x) >> 6);
    for (int e = group; e < nnz; e += stride) {
        float v = adj_vals[e];
        atomicAdd(&out[(size_t)adj_rows[e] * OUT_DIM + lane],
                  v * h[(size_t)adj_cols[e] * OUT_DIM + lane]);
    }
}

__global__ __launch_bounds__(256) void relu_kernel(float* __restrict__ out, int n)
{
    int i = (int)(blockIdx.x * blockDim.x + threadIdx.x);
    if (i < n) {
        float v = out[i];
        out[i] = v > 0.0f ? v : 0.0f;
    }
}

// ============================ launch ============================

extern "C" void kernel_launch(void* const* d_in, const int* in_sizes, int n_in,
                              void* d_out, int out_size, void* d_ws, size_t ws_size,
                              hipStream_t stream)
{
    const float* x_vals   = (const float*)d_in[0];
    const int*   x_rows   = (const int*)d_in[1];
    const int*   x_cols   = (const int*)d_in[2];
    const float* adj_vals = (const float*)d_in[3];
    const int*   adj_rows = (const int*)d_in[4];
    const int*   adj_cols = (const int*)d_in[5];
    const float* W        = (const float*)d_in[6];
    const int*   keep     = (const int*)d_in[7];

    const int x_nnz = in_sizes[0];
    const int a_nnz = in_sizes[3];

    float* out = (float*)d_out;

    // workspace layout
    char* ws = (char*)d_ws;
    size_t off = 0;
    float* h = (float*)(ws + off);          off += (size_t)N_NODES * OUT_DIM * 4;   // 25.6 MB
    float2* xs = (float2*)(ws + off);       off += (size_t)x_nnz * 8;               // 12.8 MB
    float2* as = (float2*)(ws + off);       off += (size_t)a_nnz * 8;               // 25.6 MB
    int* counts_x = (int*)(ws + off);       off += (size_t)N_NODES * 4;
    int* counts_a = (int*)(ws + off);       off += (size_t)N_NODES * 4;
    int* x_start  = (int*)(ws + off);       off += (size_t)(N_NODES + 1) * 4;
    int* a_start  = (int*)(ws + off);       off += (size_t)(N_NODES + 1) * 4;
    const size_t needed = off;

    if (ws_size >= needed) {
        // -------- CSR path --------
        hipMemsetAsync(counts_x, 0, (size_t)2 * N_NODES * 4, stream);  // counts_x+counts_a adjacent

        hist_kernel<<<2048, 256, 0, stream>>>(x_rows, keep, counts_x, x_nnz);
        hist_kernel<<<2048, 256, 0, stream>>>(adj_rows, (const int*)nullptr, counts_a, a_nnz);

        scan2_kernel<<<2, 1024, 0, stream>>>(counts_x, x_start, counts_a, a_start, N_NODES);

        scatter_x_kernel<<<2048, 256, 0, stream>>>(x_vals, x_rows, x_cols, keep,
                                                   counts_x, xs, x_nnz);
        scatter_a_kernel<<<2048, 256, 0, stream>>>(adj_vals, adj_rows, adj_cols,
                                                   counts_a, as, a_nnz);

        const int blocks = (N_NODES * 64 + 255) / 256;  // one wave per row
        spmm1_csr_kernel<<<blocks, 256, 0, stream>>>(x_start, xs, W, h);
        spmm2_csr_kernel<<<blocks, 256, 0, stream>>>(a_start, as, h, out);
    } else {
        // -------- fallback: atomic path --------
        hipMemsetAsync(h, 0, (size_t)N_NODES * OUT_DIM * 4, stream);
        hipMemsetAsync(out, 0, (size_t)out_size * 4, stream);
        spmm1_atomic_kernel<<<4096, 256, 0, stream>>>(x_vals, x_rows, x_cols, keep, W, h, x_nnz);
        spmm2_atomic_kernel<<<4096, 256, 0, stream>>>(adj_vals, adj_rows, adj_cols, h, out, a_nnz);
        relu_kernel<<<(out_size + 255) / 256, 256, 0, stream>>>(out, out_size);
    }
}

// Round 4
// 994.123 us; speedup vs baseline: 1.4603x; 1.1280x over previous
//
#include <hip/hip_runtime.h>
#include <hip/hip_bf16.h>

#define N_NODES 100000
#define IN_DIM 256
#define OUT_DIM 64
#define INV_KEEP 1.1111111111111112f  // 1/0.9

#define NSLICE 8                       // = #XCDs; dest slice must fit 4MB L2
#define ROWS_PER_SLICE ((N_NODES + NSLICE - 1) / NSLICE)  // 12500

// ======================= CSR build (XCD-sliced) =======================
// Each block owns row-slice (blockIdx % 8) -- matching the round-robin
// workgroup->XCD dispatch -- and replays the whole COO stream, touching only
// destinations in its slice. Writes to a 64B line then come from one XCD's
// L2 and merge before a single flush (kills the 7.8x write amplification).

__global__ __launch_bounds__(256) void hist_sliced_kernel(
    const int* __restrict__ rows, const int* __restrict__ keep,
    int* __restrict__ counts, int nnz)
{
    const int sid = blockIdx.x & (NSLICE - 1);
    const int lo = sid * ROWS_PER_SLICE;
    const int hi = min(lo + ROWS_PER_SLICE, N_NODES);
    int i = (int)((blockIdx.x >> 3) * blockDim.x + threadIdx.x);
    int stride = (int)((gridDim.x >> 3) * blockDim.x);
    if (keep) {
        for (int e = i; e < nnz; e += stride) {
            int r = rows[e];
            if (r >= lo && r < hi && keep[e] != 0) atomicAdd(&counts[r], 1);
        }
    } else {
        for (int e = i; e < nnz; e += stride) {
            int r = rows[e];
            if (r >= lo && r < hi) atomicAdd(&counts[r], 1);
        }
    }
}

// single-block exclusive scan of counts[n] -> start[n+1]; also rewrites
// counts[i] = start[i] (scatter cursor). block 0: (cx,sx), block 1: (ca,sa).
__global__ __launch_bounds__(1024) void scan2_kernel(
    int* __restrict__ cx, int* __restrict__ sx,
    int* __restrict__ ca, int* __restrict__ sa, int n)
{
    int* counts = (blockIdx.x == 0) ? cx : ca;
    int* start  = (blockIdx.x == 0) ? sx : sa;

    __shared__ int sums[1024];
    const int t = threadIdx.x;
    const int chunk = (n + 1023) / 1024;
    const int lo = t * chunk;
    const int hi = min(lo + chunk, n);

    int s = 0;
    for (int i = lo; i < hi; ++i) s += counts[i];
    sums[t] = s;
    __syncthreads();

    for (int off = 1; off < 1024; off <<= 1) {
        int v = (t >= off) ? sums[t - off] : 0;
        __syncthreads();
        sums[t] += v;
        __syncthreads();
    }

    int run = (t > 0) ? sums[t - 1] : 0;
    for (int i = lo; i < hi; ++i) {
        int c = counts[i];
        start[i]  = run;
        counts[i] = run;
        run += c;
    }
    if (t == 1023) start[n] = run;
}

__global__ __launch_bounds__(256) void scatter_x_sliced_kernel(
    const float* __restrict__ xv, const int* __restrict__ xr,
    const int* __restrict__ xc, const int* __restrict__ keep,
    int* __restrict__ cursor, float2* __restrict__ out, int nnz)
{
    const int sid = blockIdx.x & (NSLICE - 1);
    const int lo = sid * ROWS_PER_SLICE;
    const int hi = min(lo + ROWS_PER_SLICE, N_NODES);
    int i = (int)((blockIdx.x >> 3) * blockDim.x + threadIdx.x);
    int stride = (int)((gridDim.x >> 3) * blockDim.x);
    for (int e = i; e < nnz; e += stride) {
        int r = xr[e];
        if (r < lo || r >= hi) continue;
        if (keep[e] == 0) continue;
        int pos = atomicAdd(&cursor[r], 1);
        out[pos] = make_float2(xv[e] * INV_KEEP, __int_as_float(xc[e]));
    }
}

__global__ __launch_bounds__(256) void scatter_a_sliced_kernel(
    const float* __restrict__ av, const int* __restrict__ ar,
    const int* __restrict__ ac,
    int* __restrict__ cursor, float2* __restrict__ out, int nnz)
{
    const int sid = blockIdx.x & (NSLICE - 1);
    const int lo = sid * ROWS_PER_SLICE;
    const int hi = min(lo + ROWS_PER_SLICE, N_NODES);
    int i = (int)((blockIdx.x >> 3) * blockDim.x + threadIdx.x);
    int stride = (int)((gridDim.x >> 3) * blockDim.x);
    for (int e = i; e < nnz; e += stride) {
        int r = ar[e];
        if (r < lo || r >= hi) continue;
        int pos = atomicAdd(&cursor[r], 1);
        out[pos] = make_float2(av[e], __int_as_float(ac[e]));
    }
}

// ======================= SpMM (one wave per row) =======================

// h (bf16) = x @ W ; W rows gathered from L2 (64 KB, resident)
__global__ __launch_bounds__(256) void spmm1_csr_kernel(
    const int* __restrict__ xs_start, const float2* __restrict__ xs,
    const float* __restrict__ W, __hip_bfloat16* __restrict__ h)
{
    const int wave = (int)((blockIdx.x * blockDim.x + threadIdx.x) >> 6);
    const int lane = threadIdx.x & 63;
    if (wave >= N_NODES) return;

    const int s = xs_start[wave];
    const int e = xs_start[wave + 1];
    float acc = 0.0f;
    for (int j = s; j < e; ++j) {
        float2 p = xs[j];                       // wave-uniform 8B load
        int c = __float_as_int(p.y);
        acc += p.x * W[c * OUT_DIM + lane];     // 256B coalesced, L2-hit
    }
    h[(size_t)wave * OUT_DIM + lane] = __float2bfloat16(acc);
}

// out (f32, relu-fused) = adj @ h ; h gathered as 128B bf16 rows
__global__ __launch_bounds__(256) void spmm2_csr_kernel(
    const int* __restrict__ as_start, const float2* __restrict__ as,
    const __hip_bfloat16* __restrict__ h, float* __restrict__ out)
{
    const int wave = (int)((blockIdx.x * blockDim.x + threadIdx.x) >> 6);
    const int lane = threadIdx.x & 63;
    if (wave >= N_NODES) return;

    const int s = as_start[wave];
    const int e = as_start[wave + 1];
    float acc = 0.0f;
    for (int j = s; j < e; ++j) {
        float2 p = as[j];                       // wave-uniform 8B load
        int c = __float_as_int(p.y);
        acc += p.x * __bfloat162float(h[(size_t)c * OUT_DIM + lane]); // 128B gather
    }
    out[(size_t)wave * OUT_DIM + lane] = acc > 0.0f ? acc : 0.0f;
}

// ======================= fallback (atomic) path =======================

__global__ __launch_bounds__(256) void spmm1_atomic_kernel(
    const float* __restrict__ x_vals, const int* __restrict__ x_rows,
    const int* __restrict__ x_cols, const int* __restrict__ keep,
    const float* __restrict__ W, float* __restrict__ h, int nnz)
{
    const int lane   = threadIdx.x & 63;
    const int group  = (int)((blockIdx.x * blockDim.x + threadIdx.x) >> 6);
    const int stride = (int)((gridDim.x * blockDim.x) >> 6);
    for (int e = group; e < nnz; e += stride) {
        float v = (keep[e] != 0) ? x_vals[e] * INV_KEEP : 0.0f;
        if (v != 0.0f)
            atomicAdd(&h[(size_t)x_rows[e] * OUT_DIM + lane],
                      v * W[x_cols[e] * OUT_DIM + lane]);
    }
}

__global__ __launch_bounds__(256) void spmm2_atomic_kernel(
    const float* __restrict__ adj_vals, const int* __restrict__ adj_rows,
    const int* __restrict__ adj_cols, const float* __restrict__ h,
    float* __restrict__ out, int nnz)
{
    const int lane   = threadIdx.x & 63;
    const int group  = (int)((blockIdx.x * blockDim.x + threadIdx.x) >> 6);
    const int stride = (int)((gridDim.x * blockDim.x) >> 6);
    for (int e = group; e < nnz; e += stride) {
        atomicAdd(&out[(size_t)adj_rows[e] * OUT_DIM + lane],
                  adj_vals[e] * h[(size_t)adj_cols[e] * OUT_DIM + lane]);
    }
}

__global__ __launch_bounds__(256) void relu_kernel(float* __restrict__ out, int n)
{
    int i = (int)(blockIdx.x * blockDim.x + threadIdx.x);
    if (i < n) {
        float v = out[i];
        out[i] = v > 0.0f ? v : 0.0f;
    }
}

// ======================= launch =======================

extern "C" void kernel_launch(void* const* d_in, const int* in_sizes, int n_in,
                              void* d_out, int out_size, void* d_ws, size_t ws_size,
                              hipStream_t stream)
{
    const float* x_vals   = (const float*)d_in[0];
    const int*   x_rows   = (const int*)d_in[1];
    const int*   x_cols   = (const int*)d_in[2];
    const float* adj_vals = (const float*)d_in[3];
    const int*   adj_rows = (const int*)d_in[4];
    const int*   adj_cols = (const int*)d_in[5];
    const float* W        = (const float*)d_in[6];
    const int*   keep     = (const int*)d_in[7];

    const int x_nnz = in_sizes[0];
    const int a_nnz = in_sizes[3];

    float* out = (float*)d_out;

    // workspace layout (8B-aligned chunks first)
    char* ws = (char*)d_ws;
    size_t off = 0;
    float2* xs = (float2*)(ws + off);            off += (size_t)x_nnz * 8;           // 12.8 MB
    float2* as = (float2*)(ws + off);            off += (size_t)a_nnz * 8;           // 25.6 MB
    __hip_bfloat16* hb = (__hip_bfloat16*)(ws + off); off += (size_t)N_NODES * OUT_DIM * 2; // 12.8 MB
    int* counts_x = (int*)(ws + off);            off += (size_t)N_NODES * 4;
    int* counts_a = (int*)(ws + off);            off += (size_t)N_NODES * 4;
    int* x_start  = (int*)(ws + off);            off += (size_t)(N_NODES + 1) * 4;
    int* a_start  = (int*)(ws + off);            off += (size_t)(N_NODES + 1) * 4;
    const size_t needed = off;

    if (ws_size >= needed) {
        // -------- sliced-CSR path --------
        hipMemsetAsync(counts_x, 0, (size_t)2 * N_NODES * 4, stream);

        hist_sliced_kernel<<<2048, 256, 0, stream>>>(x_rows, keep, counts_x, x_nnz);
        hist_sliced_kernel<<<2048, 256, 0, stream>>>(adj_rows, (const int*)nullptr, counts_a, a_nnz);

        scan2_kernel<<<2, 1024, 0, stream>>>(counts_x, x_start, counts_a, a_start, N_NODES);

        scatter_x_sliced_kernel<<<2048, 256, 0, stream>>>(x_vals, x_rows, x_cols, keep,
                                                          counts_x, xs, x_nnz);
        scatter_a_sliced_kernel<<<2048, 256, 0, stream>>>(adj_vals, adj_rows, adj_cols,
                                                          counts_a, as, a_nnz);

        const int blocks = (N_NODES * 64 + 255) / 256;  // one wave per row
        spmm1_csr_kernel<<<blocks, 256, 0, stream>>>(x_start, xs, W, hb);
        spmm2_csr_kernel<<<blocks, 256, 0, stream>>>(a_start, as, hb, out);
    } else {
        // -------- fallback: atomic path --------
        float* hf = (float*)d_ws;
        hipMemsetAsync(hf, 0, (size_t)N_NODES * OUT_DIM * 4, stream);
        hipMemsetAsync(out, 0, (size_t)out_size * 4, stream);
        spmm1_atomic_kernel<<<4096, 256, 0, stream>>>(x_vals, x_rows, x_cols, keep, W, hf, x_nnz);
        spmm2_atomic_kernel<<<4096, 256, 0, stream>>>(adj_vals, adj_rows, adj_cols, hf, out, a_nnz);
        relu_kernel<<<(out_size + 255) / 256, 256, 0, stream>>>(out, out_size);
    }
}

// Round 5
// 779.172 us; speedup vs baseline: 1.8632x; 1.2759x over previous
//
#include <hip/hip_runtime.h>
#include <hip/hip_bf16.h>

#define N_NODES 100000
#define IN_DIM 256
#define OUT_DIM 64
#define INV_KEEP 1.1111111111111112f  // 1/0.9

#define NSLICE 8                       // = #XCDs; dest slice must fit 4MB L2
#define ROWS_PER_SLICE ((N_NODES + NSLICE - 1) / NSLICE)  // 12500

// ======================= CSR build (XCD-sliced) =======================

__global__ __launch_bounds__(256) void hist_sliced_kernel(
    const int* __restrict__ rows, const int* __restrict__ keep,
    int* __restrict__ counts, int nnz)
{
    const int sid = blockIdx.x & (NSLICE - 1);
    const int lo = sid * ROWS_PER_SLICE;
    const int hi = min(lo + ROWS_PER_SLICE, N_NODES);
    int i = (int)((blockIdx.x >> 3) * blockDim.x + threadIdx.x);
    int stride = (int)((gridDim.x >> 3) * blockDim.x);
    if (keep) {
        for (int e = i; e < nnz; e += stride) {
            int r = rows[e];
            if (r >= lo && r < hi && keep[e] != 0) atomicAdd(&counts[r], 1);
        }
    } else {
        for (int e = i; e < nnz; e += stride) {
            int r = rows[e];
            if (r >= lo && r < hi) atomicAdd(&counts[r], 1);
        }
    }
}

__global__ __launch_bounds__(1024) void scan2_kernel(
    int* __restrict__ cx, int* __restrict__ sx,
    int* __restrict__ ca, int* __restrict__ sa, int n)
{
    int* counts = (blockIdx.x == 0) ? cx : ca;
    int* start  = (blockIdx.x == 0) ? sx : sa;

    __shared__ int sums[1024];
    const int t = threadIdx.x;
    const int chunk = (n + 1023) / 1024;
    const int lo = t * chunk;
    const int hi = min(lo + chunk, n);

    int s = 0;
    for (int i = lo; i < hi; ++i) s += counts[i];
    sums[t] = s;
    __syncthreads();

    for (int off = 1; off < 1024; off <<= 1) {
        int v = (t >= off) ? sums[t - off] : 0;
        __syncthreads();
        sums[t] += v;
        __syncthreads();
    }

    int run = (t > 0) ? sums[t - 1] : 0;
    for (int i = lo; i < hi; ++i) {
        int c = counts[i];
        start[i]  = run;
        counts[i] = run;
        run += c;
    }
    if (t == 1023) start[n] = run;
}

__global__ __launch_bounds__(256) void scatter_x_sliced_kernel(
    const float* __restrict__ xv, const int* __restrict__ xr,
    const int* __restrict__ xc, const int* __restrict__ keep,
    int* __restrict__ cursor, float2* __restrict__ out, int nnz)
{
    const int sid = blockIdx.x & (NSLICE - 1);
    const int lo = sid * ROWS_PER_SLICE;
    const int hi = min(lo + ROWS_PER_SLICE, N_NODES);
    int i = (int)((blockIdx.x >> 3) * blockDim.x + threadIdx.x);
    int stride = (int)((gridDim.x >> 3) * blockDim.x);
    for (int e = i; e < nnz; e += stride) {
        int r = xr[e];
        if (r < lo || r >= hi) continue;
        if (keep[e] == 0) continue;
        int pos = atomicAdd(&cursor[r], 1);
        out[pos] = make_float2(xv[e] * INV_KEEP, __int_as_float(xc[e]));
    }
}

__global__ __launch_bounds__(256) void scatter_a_sliced_kernel(
    const float* __restrict__ av, const int* __restrict__ ar,
    const int* __restrict__ ac,
    int* __restrict__ cursor, float2* __restrict__ out, int nnz)
{
    const int sid = blockIdx.x & (NSLICE - 1);
    const int lo = sid * ROWS_PER_SLICE;
    const int hi = min(lo + ROWS_PER_SLICE, N_NODES);
    int i = (int)((blockIdx.x >> 3) * blockDim.x + threadIdx.x);
    int stride = (int)((gridDim.x >> 3) * blockDim.x);
    for (int e = i; e < nnz; e += stride) {
        int r = ar[e];
        if (r < lo || r >= hi) continue;
        int pos = atomicAdd(&cursor[r], 1);
        out[pos] = make_float2(av[e], __int_as_float(ac[e]));
    }
}

// ======================= SpMM (one wave per row, MLP-unrolled) =======================

// h (bf16) = x @ W ; W rows are L2-resident (64 KB). Unroll 4 for MLP.
__global__ __launch_bounds__(256) void spmm1_csr_kernel(
    const int* __restrict__ xs_start, const float2* __restrict__ xs,
    const float* __restrict__ W, __hip_bfloat16* __restrict__ h)
{
    const int wave = (int)((blockIdx.x * blockDim.x + threadIdx.x) >> 6);
    const int lane = threadIdx.x & 63;
    if (wave >= N_NODES) return;

    const int s = xs_start[wave];
    const int e = xs_start[wave + 1];
    float acc = 0.0f;
    int j = s;
    for (; j + 4 <= e; j += 4) {
        float2 p0 = xs[j + 0];
        float2 p1 = xs[j + 1];
        float2 p2 = xs[j + 2];
        float2 p3 = xs[j + 3];
        float g0 = W[__float_as_int(p0.y) * OUT_DIM + lane];
        float g1 = W[__float_as_int(p1.y) * OUT_DIM + lane];
        float g2 = W[__float_as_int(p2.y) * OUT_DIM + lane];
        float g3 = W[__float_as_int(p3.y) * OUT_DIM + lane];
        acc += p0.x * g0;
        acc += p1.x * g1;
        acc += p2.x * g2;
        acc += p3.x * g3;
    }
    for (; j < e; ++j) {
        float2 p = xs[j];
        acc += p.x * W[__float_as_int(p.y) * OUT_DIM + lane];
    }
    h[(size_t)wave * OUT_DIM + lane] = __float2bfloat16(acc);
}

// out (f32, relu-fused) = adj @ h ; h bf16 rows (128B gathers). Unroll 8 for MLP.
__global__ __launch_bounds__(256) void spmm2_csr_kernel(
    const int* __restrict__ as_start, const float2* __restrict__ as,
    const __hip_bfloat16* __restrict__ h, float* __restrict__ out)
{
    const int wave = (int)((blockIdx.x * blockDim.x + threadIdx.x) >> 6);
    const int lane = threadIdx.x & 63;
    if (wave >= N_NODES) return;

    const int s = as_start[wave];
    const int e = as_start[wave + 1];
    float acc = 0.0f;
    int j = s;
    for (; j + 8 <= e; j += 8) {
        float2 p0 = as[j + 0];
        float2 p1 = as[j + 1];
        float2 p2 = as[j + 2];
        float2 p3 = as[j + 3];
        float2 p4 = as[j + 4];
        float2 p5 = as[j + 5];
        float2 p6 = as[j + 6];
        float2 p7 = as[j + 7];
        float g0 = __bfloat162float(h[(size_t)__float_as_int(p0.y) * OUT_DIM + lane]);
        float g1 = __bfloat162float(h[(size_t)__float_as_int(p1.y) * OUT_DIM + lane]);
        float g2 = __bfloat162float(h[(size_t)__float_as_int(p2.y) * OUT_DIM + lane]);
        float g3 = __bfloat162float(h[(size_t)__float_as_int(p3.y) * OUT_DIM + lane]);
        float g4 = __bfloat162float(h[(size_t)__float_as_int(p4.y) * OUT_DIM + lane]);
        float g5 = __bfloat162float(h[(size_t)__float_as_int(p5.y) * OUT_DIM + lane]);
        float g6 = __bfloat162float(h[(size_t)__float_as_int(p6.y) * OUT_DIM + lane]);
        float g7 = __bfloat162float(h[(size_t)__float_as_int(p7.y) * OUT_DIM + lane]);
        acc += p0.x * g0;
        acc += p1.x * g1;
        acc += p2.x * g2;
        acc += p3.x * g3;
        acc += p4.x * g4;
        acc += p5.x * g5;
        acc += p6.x * g6;
        acc += p7.x * g7;
    }
    for (; j < e; ++j) {
        float2 p = as[j];
        acc += p.x * __bfloat162float(h[(size_t)__float_as_int(p.y) * OUT_DIM + lane]);
    }
    out[(size_t)wave * OUT_DIM + lane] = acc > 0.0f ? acc : 0.0f;
}

// ======================= fallback (atomic) path =======================

__global__ __launch_bounds__(256) void spmm1_atomic_kernel(
    const float* __restrict__ x_vals, const int* __restrict__ x_rows,
    const int* __restrict__ x_cols, const int* __restrict__ keep,
    const float* __restrict__ W, float* __restrict__ h, int nnz)
{
    const int lane   = threadIdx.x & 63;
    const int group  = (int)((blockIdx.x * blockDim.x + threadIdx.x) >> 6);
    const int stride = (int)((gridDim.x * blockDim.x) >> 6);
    for (int e = group; e < nnz; e += stride) {
        float v = (keep[e] != 0) ? x_vals[e] * INV_KEEP : 0.0f;
        if (v != 0.0f)
            atomicAdd(&h[(size_t)x_rows[e] * OUT_DIM + lane],
                      v * W[x_cols[e] * OUT_DIM + lane]);
    }
}

__global__ __launch_bounds__(256) void spmm2_atomic_kernel(
    const float* __restrict__ adj_vals, const int* __restrict__ adj_rows,
    const int* __restrict__ adj_cols, const float* __restrict__ h,
    float* __restrict__ out, int nnz)
{
    const int lane   = threadIdx.x & 63;
    const int group  = (int)((blockIdx.x * blockDim.x + threadIdx.x) >> 6);
    const int stride = (int)((gridDim.x * blockDim.x) >> 6);
    for (int e = group; e < nnz; e += stride) {
        atomicAdd(&out[(size_t)adj_rows[e] * OUT_DIM + lane],
                  adj_vals[e] * h[(size_t)adj_cols[e] * OUT_DIM + lane]);
    }
}

__global__ __launch_bounds__(256) void relu_kernel(float* __restrict__ out, int n)
{
    int i = (int)(blockIdx.x * blockDim.x + threadIdx.x);
    if (i < n) {
        float v = out[i];
        out[i] = v > 0.0f ? v : 0.0f;
    }
}

// ======================= launch =======================

extern "C" void kernel_launch(void* const* d_in, const int* in_sizes, int n_in,
                              void* d_out, int out_size, void* d_ws, size_t ws_size,
                              hipStream_t stream)
{
    const float* x_vals   = (const float*)d_in[0];
    const int*   x_rows   = (const int*)d_in[1];
    const int*   x_cols   = (const int*)d_in[2];
    const float* adj_vals = (const float*)d_in[3];
    const int*   adj_rows = (const int*)d_in[4];
    const int*   adj_cols = (const int*)d_in[5];
    const float* W        = (const float*)d_in[6];
    const int*   keep     = (const int*)d_in[7];

    const int x_nnz = in_sizes[0];
    const int a_nnz = in_sizes[3];

    float* out = (float*)d_out;

    // workspace layout (8B-aligned chunks first)
    char* ws = (char*)d_ws;
    size_t off = 0;
    float2* xs = (float2*)(ws + off);            off += (size_t)x_nnz * 8;           // 12.8 MB
    float2* as = (float2*)(ws + off);            off += (size_t)a_nnz * 8;           // 25.6 MB
    __hip_bfloat16* hb = (__hip_bfloat16*)(ws + off); off += (size_t)N_NODES * OUT_DIM * 2; // 12.8 MB
    int* counts_x = (int*)(ws + off);            off += (size_t)N_NODES * 4;
    int* counts_a = (int*)(ws + off);            off += (size_t)N_NODES * 4;
    int* x_start  = (int*)(ws + off);            off += (size_t)(N_NODES + 1) * 4;
    int* a_start  = (int*)(ws + off);            off += (size_t)(N_NODES + 1) * 4;
    const size_t needed = off;

    if (ws_size >= needed) {
        // -------- sliced-CSR path --------
        hipMemsetAsync(counts_x, 0, (size_t)2 * N_NODES * 4, stream);

        hist_sliced_kernel<<<2048, 256, 0, stream>>>(x_rows, keep, counts_x, x_nnz);
        hist_sliced_kernel<<<2048, 256, 0, stream>>>(adj_rows, (const int*)nullptr, counts_a, a_nnz);

        scan2_kernel<<<2, 1024, 0, stream>>>(counts_x, x_start, counts_a, a_start, N_NODES);

        scatter_x_sliced_kernel<<<2048, 256, 0, stream>>>(x_vals, x_rows, x_cols, keep,
                                                          counts_x, xs, x_nnz);
        scatter_a_sliced_kernel<<<2048, 256, 0, stream>>>(adj_vals, adj_rows, adj_cols,
                                                          counts_a, as, a_nnz);

        const int blocks = (N_NODES * 64 + 255) / 256;  // one wave per row
        spmm1_csr_kernel<<<blocks, 256, 0, stream>>>(x_start, xs, W, hb);
        spmm2_csr_kernel<<<blocks, 256, 0, stream>>>(a_start, as, hb, out);
    } else {
        // -------- fallback: atomic path --------
        float* hf = (float*)d_ws;
        hipMemsetAsync(hf, 0, (size_t)N_NODES * OUT_DIM * 4, stream);
        hipMemsetAsync(out, 0, (size_t)out_size * 4, stream);
        spmm1_atomic_kernel<<<4096, 256, 0, stream>>>(x_vals, x_rows, x_cols, keep, W, hf, x_nnz);
        spmm2_atomic_kernel<<<4096, 256, 0, stream>>>(adj_vals, adj_rows, adj_cols, hf, out, a_nnz);
        relu_kernel<<<(out_size + 255) / 256, 256, 0, stream>>>(out, out_size);
    }
}

// Round 6
// 572.690 us; speedup vs baseline: 2.5350x; 1.3605x over previous
//
#include <hip/hip_runtime.h>
#include <hip/hip_bf16.h>

#define N_NODES 100000
#define IN_DIM 256
#define OUT_DIM 64
#define INV_KEEP 1.1111111111111112f  // 1/0.9

#define NSLICE 8                       // = #XCDs; dest slice must fit 4MB L2
#define ROWS_PER_SLICE ((N_NODES + NSLICE - 1) / NSLICE)  // 12500

// multi-block scan geometry: 4 elems/thread, 1024 elems/block, 100 blocks/array
#define SCAN_PT 4
#define SCAN_BE (256 * SCAN_PT)                       // 1024
#define SCAN_NB ((N_NODES + SCAN_BE - 1) / SCAN_BE)   // 98 -> use computed

// ======================= CSR build (XCD-sliced) =======================

__global__ __launch_bounds__(256) void hist_sliced_kernel(
    const int* __restrict__ rows, const int* __restrict__ keep,
    int* __restrict__ counts, int nnz)
{
    const int sid = blockIdx.x & (NSLICE - 1);
    const int lo = sid * ROWS_PER_SLICE;
    const int hi = min(lo + ROWS_PER_SLICE, N_NODES);
    int i = (int)((blockIdx.x >> 3) * blockDim.x + threadIdx.x);
    int stride = (int)((gridDim.x >> 3) * blockDim.x);
    if (keep) {
        for (int e = i; e < nnz; e += stride) {
            int r = rows[e];
            if (r >= lo && r < hi && keep[e] != 0) atomicAdd(&counts[r], 1);
        }
    } else {
        for (int e = i; e < nnz; e += stride) {
            int r = rows[e];
            if (r >= lo && r < hi) atomicAdd(&counts[r], 1);
        }
    }
}

// ---- 3-pass exclusive scan over two arrays (cx->sx, ca->sa) ----
// pass 1: per-block partial sums. grid = 2*SCAN_NB.
__global__ __launch_bounds__(256) void scan_pass1_kernel(
    const int* __restrict__ cx, const int* __restrict__ ca,
    int* __restrict__ blocksums, int nb)
{
    const int arr = blockIdx.x / nb;
    const int b   = blockIdx.x % nb;
    const int* c  = arr ? ca : cx;
    const int t   = threadIdx.x;
    const int base = b * SCAN_BE + t * SCAN_PT;

    int s = 0;
#pragma unroll
    for (int k = 0; k < SCAN_PT; ++k) {
        int i = base + k;
        if (i < N_NODES) s += c[i];
    }
    __shared__ int lds[256];
    lds[t] = s;
    __syncthreads();
    for (int off = 128; off > 0; off >>= 1) {
        if (t < off) lds[t] += lds[t + off];
        __syncthreads();
    }
    if (t == 0) blocksums[blockIdx.x] = lds[0];
}

// pass 2: one block scans blocksums (exclusive, segmented per array).
// slot layout: array a's block b -> LDS slot a*128 + b  (nb <= 128 required)
__global__ __launch_bounds__(256) void scan_pass2_kernel(
    int* __restrict__ blocksums, int nb)
{
    const int t = threadIdx.x;
    const int arr = t >> 7;
    const int b   = t & 127;
    __shared__ int lds[256];
    lds[t] = (b < nb) ? blocksums[arr * nb + b] : 0;
    __syncthreads();
    // segmented Hillis-Steele (inclusive) within each 128-slot half
    for (int off = 1; off <= 64; off <<= 1) {
        int v = ((t & 127) >= off) ? lds[t - off] : 0;
        __syncthreads();
        lds[t] += v;
        __syncthreads();
    }
    if (b < nb)
        blocksums[arr * nb + b] = (b > 0) ? lds[t - 1] : 0;  // exclusive
}

// pass 3: per-block exclusive scan + block offset; writes start[] and
// rewrites counts[] as the scatter cursor. grid = 2*SCAN_NB.
__global__ __launch_bounds__(256) void scan_pass3_kernel(
    int* __restrict__ cx, int* __restrict__ sx,
    int* __restrict__ ca, int* __restrict__ sa,
    const int* __restrict__ blocksums, int nb)
{
    const int arr = blockIdx.x / nb;
    const int b   = blockIdx.x % nb;
    int* counts = arr ? ca : cx;
    int* start  = arr ? sa : sx;
    const int t = threadIdx.x;
    const int base = b * SCAN_BE + t * SCAN_PT;

    int vals[SCAN_PT];
    int s = 0;
#pragma unroll
    for (int k = 0; k < SCAN_PT; ++k) {
        int i = base + k;
        vals[k] = (i < N_NODES) ? counts[i] : 0;
        s += vals[k];
    }
    __shared__ int lds[256];
    lds[t] = s;
    __syncthreads();
    for (int off = 1; off <= 128; off <<= 1) {
        int v = (t >= off) ? lds[t - off] : 0;
        __syncthreads();
        lds[t] += v;
        __syncthreads();
    }
    int run = ((t > 0) ? lds[t - 1] : 0) + blocksums[blockIdx.x];
#pragma unroll
    for (int k = 0; k < SCAN_PT; ++k) {
        int i = base + k;
        if (i < N_NODES) {
            start[i]  = run;
            counts[i] = run;
            run += vals[k];
            if (i == N_NODES - 1) start[N_NODES] = run;  // array total
        }
    }
}

__global__ __launch_bounds__(256) void scatter_x_sliced_kernel(
    const float* __restrict__ xv, const int* __restrict__ xr,
    const int* __restrict__ xc, const int* __restrict__ keep,
    int* __restrict__ cursor, float2* __restrict__ out, int nnz)
{
    const int sid = blockIdx.x & (NSLICE - 1);
    const int lo = sid * ROWS_PER_SLICE;
    const int hi = min(lo + ROWS_PER_SLICE, N_NODES);
    int i = (int)((blockIdx.x >> 3) * blockDim.x + threadIdx.x);
    int stride = (int)((gridDim.x >> 3) * blockDim.x);
    for (int e = i; e < nnz; e += stride) {
        int r = xr[e];
        if (r < lo || r >= hi) continue;
        if (keep[e] == 0) continue;
        int pos = atomicAdd(&cursor[r], 1);
        out[pos] = make_float2(xv[e] * INV_KEEP, __int_as_float(xc[e]));
    }
}

__global__ __launch_bounds__(256) void scatter_a_sliced_kernel(
    const float* __restrict__ av, const int* __restrict__ ar,
    const int* __restrict__ ac,
    int* __restrict__ cursor, float2* __restrict__ out, int nnz)
{
    const int sid = blockIdx.x & (NSLICE - 1);
    const int lo = sid * ROWS_PER_SLICE;
    const int hi = min(lo + ROWS_PER_SLICE, N_NODES);
    int i = (int)((blockIdx.x >> 3) * blockDim.x + threadIdx.x);
    int stride = (int)((gridDim.x >> 3) * blockDim.x);
    for (int e = i; e < nnz; e += stride) {
        int r = ar[e];
        if (r < lo || r >= hi) continue;
        int pos = atomicAdd(&cursor[r], 1);
        out[pos] = make_float2(av[e], __int_as_float(ac[e]));
    }
}

// ======================= SpMM (one wave per row, MLP-unrolled) =======================

__global__ __launch_bounds__(256) void spmm1_csr_kernel(
    const int* __restrict__ xs_start, const float2* __restrict__ xs,
    const float* __restrict__ W, __hip_bfloat16* __restrict__ h)
{
    const int wave = (int)((blockIdx.x * blockDim.x + threadIdx.x) >> 6);
    const int lane = threadIdx.x & 63;
    if (wave >= N_NODES) return;

    const int s = xs_start[wave];
    const int e = xs_start[wave + 1];
    float acc = 0.0f;
    int j = s;
    for (; j + 4 <= e; j += 4) {
        float2 p0 = xs[j + 0];
        float2 p1 = xs[j + 1];
        float2 p2 = xs[j + 2];
        float2 p3 = xs[j + 3];
        float g0 = W[__float_as_int(p0.y) * OUT_DIM + lane];
        float g1 = W[__float_as_int(p1.y) * OUT_DIM + lane];
        float g2 = W[__float_as_int(p2.y) * OUT_DIM + lane];
        float g3 = W[__float_as_int(p3.y) * OUT_DIM + lane];
        acc += p0.x * g0;
        acc += p1.x * g1;
        acc += p2.x * g2;
        acc += p3.x * g3;
    }
    for (; j < e; ++j) {
        float2 p = xs[j];
        acc += p.x * W[__float_as_int(p.y) * OUT_DIM + lane];
    }
    h[(size_t)wave * OUT_DIM + lane] = __float2bfloat16(acc);
}

__global__ __launch_bounds__(256) void spmm2_csr_kernel(
    const int* __restrict__ as_start, const float2* __restrict__ as,
    const __hip_bfloat16* __restrict__ h, float* __restrict__ out)
{
    const int wave = (int)((blockIdx.x * blockDim.x + threadIdx.x) >> 6);
    const int lane = threadIdx.x & 63;
    if (wave >= N_NODES) return;

    const int s = as_start[wave];
    const int e = as_start[wave + 1];
    float acc = 0.0f;
    int j = s;
    for (; j + 8 <= e; j += 8) {
        float2 p0 = as[j + 0];
        float2 p1 = as[j + 1];
        float2 p2 = as[j + 2];
        float2 p3 = as[j + 3];
        float2 p4 = as[j + 4];
        float2 p5 = as[j + 5];
        float2 p6 = as[j + 6];
        float2 p7 = as[j + 7];
        float g0 = __bfloat162float(h[(size_t)__float_as_int(p0.y) * OUT_DIM + lane]);
        float g1 = __bfloat162float(h[(size_t)__float_as_int(p1.y) * OUT_DIM + lane]);
        float g2 = __bfloat162float(h[(size_t)__float_as_int(p2.y) * OUT_DIM + lane]);
        float g3 = __bfloat162float(h[(size_t)__float_as_int(p3.y) * OUT_DIM + lane]);
        float g4 = __bfloat162float(h[(size_t)__float_as_int(p4.y) * OUT_DIM + lane]);
        float g5 = __bfloat162float(h[(size_t)__float_as_int(p5.y) * OUT_DIM + lane]);
        float g6 = __bfloat162float(h[(size_t)__float_as_int(p6.y) * OUT_DIM + lane]);
        float g7 = __bfloat162float(h[(size_t)__float_as_int(p7.y) * OUT_DIM + lane]);
        acc += p0.x * g0;
        acc += p1.x * g1;
        acc += p2.x * g2;
        acc += p3.x * g3;
        acc += p4.x * g4;
        acc += p5.x * g5;
        acc += p6.x * g6;
        acc += p7.x * g7;
    }
    for (; j < e; ++j) {
        float2 p = as[j];
        acc += p.x * __bfloat162float(h[(size_t)__float_as_int(p.y) * OUT_DIM + lane]);
    }
    out[(size_t)wave * OUT_DIM + lane] = acc > 0.0f ? acc : 0.0f;
}

// ======================= fallback (atomic) path =======================

__global__ __launch_bounds__(256) void spmm1_atomic_kernel(
    const float* __restrict__ x_vals, const int* __restrict__ x_rows,
    const int* __restrict__ x_cols, const int* __restrict__ keep,
    const float* __restrict__ W, float* __restrict__ h, int nnz)
{
    const int lane   = threadIdx.x & 63;
    const int group  = (int)((blockIdx.x * blockDim.x + threadIdx.x) >> 6);
    const int stride = (int)((gridDim.x * blockDim.x) >> 6);
    for (int e = group; e < nnz; e += stride) {
        float v = (keep[e] != 0) ? x_vals[e] * INV_KEEP : 0.0f;
        if (v != 0.0f)
            atomicAdd(&h[(size_t)x_rows[e] * OUT_DIM + lane],
                      v * W[x_cols[e] * OUT_DIM + lane]);
    }
}

__global__ __launch_bounds__(256) void spmm2_atomic_kernel(
    const float* __restrict__ adj_vals, const int* __restrict__ adj_rows,
    const int* __restrict__ adj_cols, const float* __restrict__ h,
    float* __restrict__ out, int nnz)
{
    const int lane   = threadIdx.x & 63;
    const int group  = (int)((blockIdx.x * blockDim.x + threadIdx.x) >> 6);
    const int stride = (int)((gridDim.x * blockDim.x) >> 6);
    for (int e = group; e < nnz; e += stride) {
        atomicAdd(&out[(size_t)adj_rows[e] * OUT_DIM + lane],
                  adj_vals[e] * h[(size_t)adj_cols[e] * OUT_DIM + lane]);
    }
}

__global__ __launch_bounds__(256) void relu_kernel(float* __restrict__ out, int n)
{
    int i = (int)(blockIdx.x * blockDim.x + threadIdx.x);
    if (i < n) {
        float v = out[i];
        out[i] = v > 0.0f ? v : 0.0f;
    }
}

// ======================= launch =======================

extern "C" void kernel_launch(void* const* d_in, const int* in_sizes, int n_in,
                              void* d_out, int out_size, void* d_ws, size_t ws_size,
                              hipStream_t stream)
{
    const float* x_vals   = (const float*)d_in[0];
    const int*   x_rows   = (const int*)d_in[1];
    const int*   x_cols   = (const int*)d_in[2];
    const float* adj_vals = (const float*)d_in[3];
    const int*   adj_rows = (const int*)d_in[4];
    const int*   adj_cols = (const int*)d_in[5];
    const float* W        = (const float*)d_in[6];
    const int*   keep     = (const int*)d_in[7];

    const int x_nnz = in_sizes[0];
    const int a_nnz = in_sizes[3];

    float* out = (float*)d_out;

    // workspace layout (8B-aligned chunks first)
    char* ws = (char*)d_ws;
    size_t off = 0;
    float2* xs = (float2*)(ws + off);            off += (size_t)x_nnz * 8;           // 12.8 MB
    float2* as = (float2*)(ws + off);            off += (size_t)a_nnz * 8;           // 25.6 MB
    __hip_bfloat16* hb = (__hip_bfloat16*)(ws + off); off += (size_t)N_NODES * OUT_DIM * 2; // 12.8 MB
    int* counts_x = (int*)(ws + off);            off += (size_t)N_NODES * 4;
    int* counts_a = (int*)(ws + off);            off += (size_t)N_NODES * 4;
    int* x_start  = (int*)(ws + off);            off += (size_t)(N_NODES + 1) * 4;
    int* a_start  = (int*)(ws + off);            off += (size_t)(N_NODES + 1) * 4;
    int* blocksums = (int*)(ws + off);           off += (size_t)2 * ((N_NODES + SCAN_BE - 1) / SCAN_BE) * 4;
    const size_t needed = off;

    const int nb = (N_NODES + SCAN_BE - 1) / SCAN_BE;   // blocks per array (<=128)

    if (ws_size >= needed) {
        // -------- sliced-CSR path --------
        hipMemsetAsync(counts_x, 0, (size_t)2 * N_NODES * 4, stream);

        hist_sliced_kernel<<<2048, 256, 0, stream>>>(x_rows, keep, counts_x, x_nnz);
        hist_sliced_kernel<<<2048, 256, 0, stream>>>(adj_rows, (const int*)nullptr, counts_a, a_nnz);

        scan_pass1_kernel<<<2 * nb, 256, 0, stream>>>(counts_x, counts_a, blocksums, nb);
        scan_pass2_kernel<<<1, 256, 0, stream>>>(blocksums, nb);
        scan_pass3_kernel<<<2 * nb, 256, 0, stream>>>(counts_x, x_start, counts_a, a_start,
                                                      blocksums, nb);

        scatter_x_sliced_kernel<<<2048, 256, 0, stream>>>(x_vals, x_rows, x_cols, keep,
                                                          counts_x, xs, x_nnz);
        scatter_a_sliced_kernel<<<2048, 256, 0, stream>>>(adj_vals, adj_rows, adj_cols,
                                                          counts_a, as, a_nnz);

        const int blocks = (N_NODES * 64 + 255) / 256;  // one wave per row
        spmm1_csr_kernel<<<blocks, 256, 0, stream>>>(x_start, xs, W, hb);
        spmm2_csr_kernel<<<blocks, 256, 0, stream>>>(a_start, as, hb, out);
    } else {
        // -------- fallback: atomic path --------
        float* hf = (float*)d_ws;
        hipMemsetAsync(hf, 0, (size_t)N_NODES * OUT_DIM * 4, stream);
        hipMemsetAsync(out, 0, (size_t)out_size * 4, stream);
        spmm1_atomic_kernel<<<4096, 256, 0, stream>>>(x_vals, x_rows, x_cols, keep, W, hf, x_nnz);
        spmm2_atomic_kernel<<<4096, 256, 0, stream>>>(adj_vals, adj_rows, adj_cols, hf, out, a_nnz);
        relu_kernel<<<(out_size + 255) / 256, 256, 0, stream>>>(out, out_size);
    }
}